// Round 3
// baseline (1019.269 us; speedup 1.0000x reference)
//
#include <hip/hip_runtime.h>
#include <cstdint>
#include <cstddef>

// Problem constants
constexpr int B_  = 4;
constexpr int C_  = 512;
constexpr int CH_ = 256;
constexpr int N_  = 4096;
#define LOG2E 1.4426950408889634f

typedef float    f32x4 __attribute__((ext_vector_type(4)));
typedef _Float16 f16x8 __attribute__((ext_vector_type(8)));
typedef _Float16 f16x4 __attribute__((ext_vector_type(4)));

__device__ __forceinline__ f32x4 MFMA16(f16x8 a, f16x8 b, f32x4 c) {
  return __builtin_amdgcn_mfma_f32_16x16x32_f16(a, b, c, 0, 0, 0);
}

// async global->LDS, 16B per lane; LDS dest is wave-uniform base + lane*16
typedef const __attribute__((address_space(1))) unsigned int* gas_u32p;
typedef __attribute__((address_space(3))) unsigned int* las_u32p;
__device__ __forceinline__ void async16(const void* g, void* l) {
  __builtin_amdgcn_global_load_lds((gas_u32p)g, (las_u32p)l, 16, 0, 0);
}

// DPP 16-lane max reduction (row_ror 8/4/2/1) — VALU only, no LDS traffic
template <int CTRL>
__device__ __forceinline__ float dppmax(float x) {
  float y = __builtin_bit_cast(
      float, __builtin_amdgcn_update_dpp(0, __builtin_bit_cast(int, x), CTRL,
                                         0xF, 0xF, true));
  return fmaxf(x, y);
}
__device__ __forceinline__ float rowmax16(float x) {
  x = dppmax<0x128>(x);
  x = dppmax<0x124>(x);
  x = dppmax<0x122>(x);
  x = dppmax<0x121>(x);
  return x;
}

// ---------------------------------------------------------------------------
// Kernel 1: weight prep -> fp16. Wq scaled by LOG2E (softmax in exp2 domain).
// ---------------------------------------------------------------------------
__global__ void prep_w_kernel(const float* __restrict__ Wq,
                              const float* __restrict__ Wk,
                              const float* __restrict__ Wv,
                              _Float16* __restrict__ wq,
                              _Float16* __restrict__ wk,
                              _Float16* __restrict__ wv) {
  int i = blockIdx.x * 256 + threadIdx.x;
  if (i < CH_ * C_) {
    wq[i] = (_Float16)(Wq[i] * LOG2E);
    wk[i] = (_Float16)Wk[i];
  }
  if (i < C_ * C_) wv[i] = (_Float16)Wv[i];
}

// ---------------------------------------------------------------------------
// Kernel 2: fused projection GEMM (q, k, v in one launch; blockIdx.y selects).
//   out[o][n] = sum_c W[o][c] * X[c][n] + bias[o]
// W fp16 staged via async16 (double-buffered, one barrier/K-step); X read
// directly from global fp32 (per-lane stride-N loads, coalesced across the 16
// lm-lanes) and converted to f16 frags in-register — no transpose pass.
// mode 0 (q,k): A=X-frag, B=W-frag -> D[n][o], store [b][n][M].
// mode 1 (v):   A=W-frag, B=X-frag -> D[o][n], store [b][M][n].
// 512 thr / 8 waves; wg tile 256o x 64n; wave tile 64o x 32n.
// ---------------------------------------------------------------------------
__global__ __launch_bounds__(512, 4) void proj_kernel(
    const _Float16* __restrict__ wq, const _Float16* __restrict__ wk,
    const _Float16* __restrict__ wv, const float* __restrict__ Q,
    const float* __restrict__ K, const float* __restrict__ V,
    const float* __restrict__ bq, const float* __restrict__ bk,
    const float* __restrict__ bv, _Float16* __restrict__ qT,
    _Float16* __restrict__ kT, _Float16* __restrict__ vT) {
  __shared__ _Float16 lW[2][256 * 32];  // 16 KB per buf

  const int y = blockIdx.y;
  const _Float16* W;
  const float* X;
  const float* bias;
  _Float16* out;
  int o0 = 0, M, mode;
  float bscale = 1.0f;
  if (y == 0) {
    W = wq; X = Q; bias = bq; out = qT; M = CH_; mode = 0; bscale = LOG2E;
  } else if (y == 1) {
    W = wk; X = K; bias = bk; out = kT; M = CH_; mode = 0;
  } else {
    W = wv; X = V; bias = bv; out = vT; M = C_; mode = 1; o0 = (y - 2) * 256;
  }

  const int tid = threadIdx.x;
  const int lane = tid & 63, wave = tid >> 6;
  const int g = lane >> 4, lm = lane & 15;
  const int b = blockIdx.z;
  const int n0 = blockIdx.x * 64;
  const int wo = (wave >> 1) * 64, wn = (wave & 1) * 32;

  const _Float16* Wb = W + (size_t)o0 * C_;
  const float* Xb = X + (size_t)b * C_ * N_;

  f32x4 acc[8];
#pragma unroll
  for (int i = 0; i < 8; ++i) acc[i] = f32x4{0.f, 0.f, 0.f, 0.f};

  auto stageW = [&](int s, int buf) {
    int c0 = s * 32;
#pragma unroll
    for (int r = 0; r < 2; ++r) {  // 1024 granules of 16B
      int ci = r * 512 + tid;
      int o = ci >> 2, cg = ci & 3;
      async16(Wb + (size_t)o * C_ + c0 + cg * 8,
              (char*)&lW[buf][0] + r * 8192 + wave * 1024);
    }
  };
  stageW(0, 0);

  const int ncol = n0 + wn + lm;

  for (int s = 0; s < 16; ++s) {
    __syncthreads();  // drains async16 for buf s (vmcnt0) + protects buf reuse
    if (s < 15) stageW(s + 1, (s + 1) & 1);
    const int c0 = s * 32;
    // X frags straight from global fp32
    f16x8 xf[2];
#pragma unroll
    for (int nt = 0; nt < 2; ++nt) {
      const float* xp = Xb + (size_t)(c0 + g * 8) * N_ + ncol + nt * 16;
#pragma unroll
      for (int j = 0; j < 8; ++j) xf[nt][j] = (_Float16)xp[(size_t)j * N_];
    }
    const _Float16* pw = &lW[s & 1][0];
    f16x8 wf[4];
#pragma unroll
    for (int ot = 0; ot < 4; ++ot)
      wf[ot] = *(const f16x8*)(pw + ((wo + ot * 16 + lm) * 4 + g) * 8);
    if (mode == 0) {
#pragma unroll
      for (int nt = 0; nt < 2; ++nt)
#pragma unroll
        for (int ot = 0; ot < 4; ++ot)
          acc[nt * 4 + ot] = MFMA16(xf[nt], wf[ot], acc[nt * 4 + ot]);
    } else {
#pragma unroll
      for (int ot = 0; ot < 4; ++ot)
#pragma unroll
        for (int nt = 0; nt < 2; ++nt)
          acc[ot * 2 + nt] = MFMA16(wf[ot], xf[nt], acc[ot * 2 + nt]);
    }
  }

  if (mode == 0) {
    // D[n][o]: row=n=(g*4+r), col=o=lm
#pragma unroll
    for (int nt = 0; nt < 2; ++nt) {
#pragma unroll
      for (int ot = 0; ot < 4; ++ot) {
        int o = wo + ot * 16 + lm;
        float bv_ = bias[o] * bscale;
#pragma unroll
        for (int r = 0; r < 4; ++r) {
          int n = n0 + wn + nt * 16 + g * 4 + r;
          out[((size_t)b * N_ + n) * M + o] =
              (_Float16)(acc[nt * 4 + ot][r] + bv_);
        }
      }
    }
  } else {
    // D[o][n]: row=o=(g*4+r), col=n=lm
#pragma unroll
    for (int ot = 0; ot < 4; ++ot) {
#pragma unroll
      for (int r = 0; r < 4; ++r) {
        int o = o0 + wo + ot * 16 + g * 4 + r;
        float bv_ = bias[o];
#pragma unroll
        for (int nt = 0; nt < 2; ++nt) {
          int n = n0 + wn + nt * 16 + lm;
          out[((size_t)b * M + o) * N_ + n] =
              (_Float16)(acc[ot * 2 + nt][r] + bv_);
        }
      }
    }
  }
}

// ---------------------------------------------------------------------------
// Kernel 3: flash attention, split-K (flash-decoding).
// grid 512 = B(4) x tiles(64) x half(2) -> 2 blocks/CU co-resident, so barrier
// vmcnt drains of one block overlap the other's compute. Each block: Q-tile
// 64, keys [h*2048, h*2048+2048), 64 iters of K-tile 32.
// Half 0 writes fp32 partial O^T straight into d_out; half 1 writes f16
// partial to ws. Per-row m, l go to ws; combine_kernel renormalizes.
// Conditional O-rescale via block-uniform rflag (max rarely changes).
// ---------------------------------------------------------------------------
__global__ __launch_bounds__(512, 4) void attn_kernel(
    const _Float16* __restrict__ qT, const _Float16* __restrict__ kT,
    const _Float16* __restrict__ vN, float* __restrict__ Op0,
    _Float16* __restrict__ Op1, float* __restrict__ mbuf,
    float* __restrict__ lbuf) {
  __shared__ _Float16 stage[16384];  // 32 KB: q staging; loop uses [0:16KB) for kh
  __shared__ _Float16 P_t[64 * 40];  // P[n][m], stride 40 halves
  __shared__ float sm[128];          // [ctS][row] strip maxes
  __shared__ float al_st[64];        // per-row alpha
  __shared__ int rflag;

  const int tid = threadIdx.x;
  const int lane = tid & 63, wave = tid >> 6;
  const int g = lane >> 4, lm = lane & 15;

  // XCD-aware decode: (b,h) constant per XCD for K/V L2 locality
  const int bx = blockIdx.x;
  const int h = bx & 1;
  const int b = (bx >> 1) & 3;
  const int tile = bx >> 3;
  const int n0 = tile * 64;
  const int mbase = h * 2048;

  const int rt = wave & 3;    // S row-tile (query rows)
  const int ctS = wave >> 2;  // S col-tile (keys 0-15 / 16-31)
  const int c0w = wave * 64;  // PV channel range

  f32x4 O[4][4];  // [ct][nt]
#pragma unroll
  for (int i = 0; i < 4; ++i)
#pragma unroll
    for (int j = 0; j < 4; ++j) O[i][j] = f32x4{0.f, 0.f, 0.f, 0.f};
  f32x4 Ol[4];  // ones-row accumulator (l), meaningful on wave 7
#pragma unroll
  for (int j = 0; j < 4; ++j) Ol[j] = f32x4{0.f, 0.f, 0.f, 0.f};

  // ---- prologue: q staging (2048 granules, XOR-swizzled) ----
  const _Float16* qTb = qT + ((size_t)b * N_ + n0) * CH_;
#pragma unroll
  for (int r = 0; r < 4; ++r) {
    int ci = r * 512 + tid;
    int n = ci >> 5, cgl = ci & 31;
    int cg = cgl ^ (n & 7);
    async16(qTb + (size_t)n * CH_ + cg * 8,
            (char*)stage + r * 8192 + wave * 1024);
  }
  __syncthreads();
  f16x8 qf[8];
  {
    int n = rt * 16 + lm;
#pragma unroll
    for (int ks = 0; ks < 8; ++ks) {
      int cg = (ks * 4 + g) ^ (n & 7);
      qf[ks] = *(const f16x8*)&stage[(n * 32 + cg) * 8];
    }
  }
  __syncthreads();  // all q reads done before kh overwrites stage

  const _Float16* kTb = kT + ((size_t)b * N_ + mbase) * CH_;
  const _Float16* vNb = vN + (size_t)b * C_ * N_;

  auto stage_k = [&](int it) {
    int m0 = it * 32;
#pragma unroll
    for (int r = 0; r < 2; ++r) {  // 1024 granules, XOR-swizzled
      int ci = r * 512 + tid;
      int m = ci >> 5, cgl = ci & 31;
      int cg = cgl ^ (m & 7);
      async16(kTb + (size_t)(m0 + m) * CH_ + cg * 8,
              (char*)stage + r * 8192 + wave * 1024);
    }
  };
  stage_k(0);

  f16x8 vf[4], vfn[4];
  const _Float16* vbase[4];
#pragma unroll
  for (int ct = 0; ct < 4; ++ct)
    vbase[ct] = vNb + (size_t)(c0w + ct * 16 + lm) * N_ + mbase + g * 8;
#pragma unroll
  for (int ct = 0; ct < 4; ++ct) vf[ct] = *(const f16x8*)(vbase[ct]);

  f32x4 m_run = f32x4{-1e30f, -1e30f, -1e30f, -1e30f};
  int kfo[8];  // loop-invariant k-frag offsets
  {
    int m = ctS * 16 + lm;
#pragma unroll
    for (int ks = 0; ks < 8; ++ks)
      kfo[ks] = (m * 32 + ((ks * 4 + g) ^ (m & 7))) * 8;
  }
  f16x8 ones;
#pragma unroll
  for (int i = 0; i < 8; ++i) ones[i] = (_Float16)1.0f;

#pragma unroll 1
  for (int it = 0; it < 64; ++it) {
    __syncthreads();  // drains kh(it)+vf prefetch; protects P_t reuse
    if (tid == 0) rflag = 0;

    // ---- S: one 16x16 tile per wave, K=256 ----
    f32x4 s = f32x4{0.f, 0.f, 0.f, 0.f};
#pragma unroll
    for (int ks = 0; ks < 8; ++ks) {
      f16x8 kf = *(const f16x8*)&stage[kfo[ks]];
      s = MFMA16(qf[ks], kf, s);
    }

    // ---- strip row-max via DPP, exchange across the 2 col-waves ----
    f32x4 mx;
#pragma unroll
    for (int r = 0; r < 4; ++r) mx[r] = rowmax16(s[r]);
    if (lm == 0) *(f32x4*)&sm[ctS * 64 + rt * 16 + g * 4] = mx;
    __syncthreads();  // B — also: all kf reads complete, stage free

    // ---- prefetch next tiles (issued as early as correctness allows;
    // drained only at the NEXT top barrier, a full softmax+PV later) ----
    if (it < 63) {
      stage_k(it + 1);
      int mo = (it + 1) * 32;
#pragma unroll
      for (int ct = 0; ct < 4; ++ct)
        vfn[ct] = *(const f16x8*)(vbase[ct] + mo);
    }

    f32x4 a0 = *(const f32x4*)&sm[rt * 16 + g * 4];
    f32x4 a1 = *(const f32x4*)&sm[64 + rt * 16 + g * 4];
    f32x4 mn, alpha;
    bool bump = false;
#pragma unroll
    for (int r = 0; r < 4; ++r) {
      mn[r] = fmaxf(m_run[r], fmaxf(a0[r], a1[r]));
      alpha[r] = exp2f(m_run[r] - mn[r]);
      if (mn[r] > m_run[r]) bump = true;
      m_run[r] = mn[r];
    }
#pragma unroll
    for (int r = 0; r < 4; ++r) {
      float p = exp2f(s[r] - mn[r]);
      P_t[(rt * 16 + g * 4 + r) * 40 + ctS * 16 + lm] = (_Float16)p;
    }
    if (ctS == 0 && lm == 0) {
      *(f32x4*)&al_st[rt * 16 + g * 4] = alpha;
      if (bump) rflag = 1;
    }
    __syncthreads();  // C
    const int rf = rflag;

    // ---- rescale O only when some row's max actually increased ----
    if (rf) {
#pragma unroll
      for (int nt = 0; nt < 4; ++nt) {
        float a = al_st[nt * 16 + lm];
#pragma unroll
        for (int ct = 0; ct < 4; ++ct) {
          O[ct][nt][0] *= a; O[ct][nt][1] *= a;
          O[ct][nt][2] *= a; O[ct][nt][3] *= a;
        }
        Ol[nt][0] *= a; Ol[nt][1] *= a; Ol[nt][2] *= a; Ol[nt][3] *= a;
      }
    }

    // ---- PV: O^T[c][n] += v[c][m] * P[n][m]; wave 7 adds ones-row => l ----
#pragma unroll
    for (int nt = 0; nt < 4; ++nt) {
      f16x8 pf = *(const f16x8*)&P_t[(nt * 16 + lm) * 40 + g * 8];
#pragma unroll
      for (int ct = 0; ct < 4; ++ct) O[ct][nt] = MFMA16(vf[ct], pf, O[ct][nt]);
      if (wave == 7) Ol[nt] = MFMA16(ones, pf, Ol[nt]);
    }
#pragma unroll
    for (int ct = 0; ct < 4; ++ct) vf[ct] = vfn[ct];
  }

  // ---- epilogue: write partial O, per-row m and l ----
  const size_t hb = (size_t)(b * 2 + h) * N_;
  if (ctS == 0 && lm == 0) {
#pragma unroll
    for (int r = 0; r < 4; ++r) mbuf[hb + n0 + rt * 16 + g * 4 + r] = m_run[r];
  }
  if (wave == 7 && g == 0) {
#pragma unroll
    for (int nt = 0; nt < 4; ++nt) lbuf[hb + n0 + nt * 16 + lm] = Ol[nt][0];
  }
  if (h == 0) {
    float* ob = Op0 + (size_t)b * C_ * N_;
#pragma unroll
    for (int nt = 0; nt < 4; ++nt) {
      int n_g = n0 + nt * 16 + lm;
#pragma unroll
      for (int ct = 0; ct < 4; ++ct) {
        int cbase = c0w + ct * 16 + g * 4;
#pragma unroll
        for (int r = 0; r < 4; ++r)
          ob[(size_t)(cbase + r) * N_ + n_g] = O[ct][nt][r];
      }
    }
  } else {
    _Float16* ob = Op1 + (size_t)b * C_ * N_;
#pragma unroll
    for (int nt = 0; nt < 4; ++nt) {
      int n_g = n0 + nt * 16 + lm;
#pragma unroll
      for (int ct = 0; ct < 4; ++ct) {
        int cbase = c0w + ct * 16 + g * 4;
#pragma unroll
        for (int r = 0; r < 4; ++r)
          ob[(size_t)(cbase + r) * N_ + n_g] = (_Float16)O[ct][nt][r];
      }
    }
  }
}

// ---------------------------------------------------------------------------
// Kernel 4: combine the two K-halves + gamma scale + V residual.
// out (= d_out) holds half-0 fp32 partial on entry; Op1 holds half-1 f16.
// out = gamma * (a0*O0 + a1*O1) / (a0*l0 + a1*l1) + V
// ---------------------------------------------------------------------------
__global__ __launch_bounds__(256) void combine_kernel(
    float* __restrict__ out, const _Float16* __restrict__ Op1,
    const float* __restrict__ mbuf, const float* __restrict__ lbuf,
    const float* __restrict__ Vin, const float* __restrict__ gptr) {
  const int b = blockIdx.y;
  const int tid = threadIdx.x;
  const int n = blockIdx.x * 64 + (tid & 15) * 4;
  const int cg = tid >> 4;
  const float gamma = gptr[0];

  float s0[4], s1[4];
#pragma unroll
  for (int j = 0; j < 4; ++j) {
    float m0 = mbuf[(size_t)(b * 2 + 0) * N_ + n + j];
    float m1 = mbuf[(size_t)(b * 2 + 1) * N_ + n + j];
    float mx = fmaxf(m0, m1);
    float a0 = exp2f(m0 - mx), a1 = exp2f(m1 - mx);
    float l = a0 * lbuf[(size_t)(b * 2 + 0) * N_ + n + j] +
              a1 * lbuf[(size_t)(b * 2 + 1) * N_ + n + j];
    float inv = gamma / l;
    s0[j] = a0 * inv;
    s1[j] = a1 * inv;
  }

  const _Float16* O1b = Op1 + (size_t)b * C_ * N_;
  for (int c = cg * 32; c < cg * 32 + 32; ++c) {
    size_t idx = ((size_t)b * C_ + c) * N_ + n;
    f32x4 p0 = *(const f32x4*)(out + idx);
    f16x4 p1 = *(const f16x4*)(O1b + (size_t)c * N_ + n);
    f32x4 V = *(const f32x4*)(Vin + idx);
    f32x4 r;
#pragma unroll
    for (int j = 0; j < 4; ++j)
      r[j] = p0[j] * s0[j] + (float)p1[j] * s1[j] + V[j];
    *(f32x4*)(out + idx) = r;
  }
}

// ---------------------------------------------------------------------------
extern "C" void kernel_launch(void* const* d_in, const int* in_sizes, int n_in,
                              void* d_out, int out_size, void* d_ws, size_t ws_size,
                              hipStream_t stream) {
  const float* Q  = (const float*)d_in[0];
  const float* K  = (const float*)d_in[1];
  const float* V  = (const float*)d_in[2];
  const float* Wq = (const float*)d_in[3];
  const float* bq = (const float*)d_in[4];
  const float* Wk = (const float*)d_in[5];
  const float* bk = (const float*)d_in[6];
  const float* Wv = (const float*)d_in[7];
  const float* bv = (const float*)d_in[8];
  const float* gm = (const float*)d_in[9];
  float* out = (float*)d_out;

  // workspace carve (~50 MB)
  char* p = (char*)d_ws;
  _Float16* wq = (_Float16*)p; p += (size_t)CH_ * C_ * 2;
  _Float16* wk = (_Float16*)p; p += (size_t)CH_ * C_ * 2;
  _Float16* wv = (_Float16*)p; p += (size_t)C_ * C_ * 2;
  _Float16* qT = (_Float16*)p; p += (size_t)B_ * N_ * CH_ * 2;
  _Float16* kT = (_Float16*)p; p += (size_t)B_ * N_ * CH_ * 2;
  _Float16* vT = (_Float16*)p; p += (size_t)B_ * C_ * N_ * 2;
  _Float16* Op1 = (_Float16*)p; p += (size_t)B_ * C_ * N_ * 2;  // half-1 partial
  float* mbuf = (float*)p; p += (size_t)B_ * 2 * N_ * 4;
  float* lbuf = (float*)p; p += (size_t)B_ * 2 * N_ * 4;

  prep_w_kernel<<<(C_ * C_) / 256, 256, 0, stream>>>(Wq, Wk, Wv, wq, wk, wv);

  // fused q/k/v projections, one launch (y: 0=q, 1=k, 2,3=v halves)
  proj_kernel<<<dim3(N_ / 64, 4, B_), 512, 0, stream>>>(
      wq, wk, wv, Q, K, V, bq, bk, bv, qT, kT, vT);

  // split-K flash attention: half-0 partial -> d_out (fp32), half-1 -> Op1
  attn_kernel<<<512, 512, 0, stream>>>(qT, kT, vT, out, Op1, mbuf, lbuf);

  combine_kernel<<<dim3(N_ / 64, B_), 256, 0, stream>>>(out, Op1, mbuf, lbuf,
                                                        V, gm);
}

// Round 4
// 401.524 us; speedup vs baseline: 2.5385x; 2.5385x over previous
//
#include <hip/hip_runtime.h>
#include <cstdint>
#include <cstddef>

// Problem constants
constexpr int B_  = 4;
constexpr int C_  = 512;
constexpr int CH_ = 256;
constexpr int N_  = 4096;
#define LOG2E 1.4426950408889634f

typedef float    f32x4 __attribute__((ext_vector_type(4)));
typedef _Float16 f16x8 __attribute__((ext_vector_type(8)));
typedef _Float16 f16x4 __attribute__((ext_vector_type(4)));

__device__ __forceinline__ f32x4 MFMA16(f16x8 a, f16x8 b, f32x4 c) {
  return __builtin_amdgcn_mfma_f32_16x16x32_f16(a, b, c, 0, 0, 0);
}

// async global->LDS, 16B per lane; LDS dest is wave-uniform base + lane*16
typedef const __attribute__((address_space(1))) unsigned int* gas_u32p;
typedef __attribute__((address_space(3))) unsigned int* las_u32p;
__device__ __forceinline__ void async16(const void* g, void* l) {
  __builtin_amdgcn_global_load_lds((gas_u32p)g, (las_u32p)l, 16, 0, 0);
}

// DPP 16-lane reductions (row_ror 8/4/2/1) — VALU only, no LDS traffic
template <int CTRL>
__device__ __forceinline__ float dppmax(float x) {
  float y = __builtin_bit_cast(
      float, __builtin_amdgcn_update_dpp(0, __builtin_bit_cast(int, x), CTRL,
                                         0xF, 0xF, true));
  return fmaxf(x, y);
}
template <int CTRL>
__device__ __forceinline__ float dppadd(float x) {
  float y = __builtin_bit_cast(
      float, __builtin_amdgcn_update_dpp(0, __builtin_bit_cast(int, x), CTRL,
                                         0xF, 0xF, true));
  return x + y;
}
__device__ __forceinline__ float rowmax16(float x) {
  x = dppmax<0x128>(x); x = dppmax<0x124>(x);
  x = dppmax<0x122>(x); x = dppmax<0x121>(x);
  return x;
}
__device__ __forceinline__ float rowsum16(float x) {
  x = dppadd<0x128>(x); x = dppadd<0x124>(x);
  x = dppadd<0x122>(x); x = dppadd<0x121>(x);
  return x;
}

// ---------------------------------------------------------------------------
// Kernel 1: weight prep -> fp16. Wq scaled by LOG2E (softmax in exp2 domain).
// ---------------------------------------------------------------------------
__global__ void prep_w_kernel(const float* __restrict__ Wq,
                              const float* __restrict__ Wk,
                              const float* __restrict__ Wv,
                              _Float16* __restrict__ wq,
                              _Float16* __restrict__ wk,
                              _Float16* __restrict__ wv) {
  int i = blockIdx.x * 256 + threadIdx.x;
  if (i < CH_ * C_) {
    wq[i] = (_Float16)(Wq[i] * LOG2E);
    wk[i] = (_Float16)Wk[i];
  }
  if (i < C_ * C_) wv[i] = (_Float16)Wv[i];
}

// ---------------------------------------------------------------------------
// Kernel 2: fused projection GEMM (q, k, v in one launch; blockIdx.y selects).
// W fp16 via async16 (double-buffered); X fp32 PREFETCHED one K-step ahead
// into registers (R3 loaded X right before use -> 16 exposed latencies/step).
// s-loop fully unrolled so the X prefetch double-buffer stays in registers.
// ---------------------------------------------------------------------------
__global__ __launch_bounds__(512, 2) void proj_kernel(
    const _Float16* __restrict__ wq, const _Float16* __restrict__ wk,
    const _Float16* __restrict__ wv, const float* __restrict__ Q,
    const float* __restrict__ K, const float* __restrict__ V,
    const float* __restrict__ bq, const float* __restrict__ bk,
    const float* __restrict__ bv, _Float16* __restrict__ qT,
    _Float16* __restrict__ kT, _Float16* __restrict__ vT) {
  __shared__ __align__(16) _Float16 lW[2][256 * 32];  // 16 KB per buf

  const int y = blockIdx.y;
  const _Float16* W;
  const float* X;
  const float* bias;
  _Float16* out;
  int o0 = 0, M, mode;
  float bscale = 1.0f;
  if (y == 0) {
    W = wq; X = Q; bias = bq; out = qT; M = CH_; mode = 0; bscale = LOG2E;
  } else if (y == 1) {
    W = wk; X = K; bias = bk; out = kT; M = CH_; mode = 0;
  } else {
    W = wv; X = V; bias = bv; out = vT; M = C_; mode = 1; o0 = (y - 2) * 256;
  }

  const int tid = threadIdx.x;
  const int lane = tid & 63, wave = tid >> 6;
  const int g = lane >> 4, lm = lane & 15;
  const int b = blockIdx.z;
  const int n0 = blockIdx.x * 64;
  const int wo = (wave >> 1) * 64, wn = (wave & 1) * 32;

  const _Float16* Wb = W + (size_t)o0 * C_;
  const float* Xb = X + (size_t)b * C_ * N_;
  const int ncol = n0 + wn + lm;

  f32x4 acc[8];
#pragma unroll
  for (int i = 0; i < 8; ++i) acc[i] = f32x4{0.f, 0.f, 0.f, 0.f};

  auto stageW = [&](int s, int buf) {
    int c0 = s * 32;
#pragma unroll
    for (int r = 0; r < 2; ++r) {
      int ci = r * 512 + tid;
      int o = ci >> 2, cg = ci & 3;
      async16(Wb + (size_t)o * C_ + c0 + cg * 8,
              (char*)&lW[buf][0] + r * 8192 + wave * 1024);
    }
  };

  float xr[2][2][8];  // X prefetch double-buffer (registers; s-loop unrolled)
  auto loadX = [&](int s, int buf) {
    int c0 = s * 32;
#pragma unroll
    for (int nt = 0; nt < 2; ++nt) {
      const float* xp = Xb + (size_t)(c0 + g * 8) * N_ + ncol + nt * 16;
#pragma unroll
      for (int j = 0; j < 8; ++j) xr[buf][nt][j] = xp[(size_t)j * N_];
    }
  };

  stageW(0, 0);
  loadX(0, 0);

#pragma unroll
  for (int s = 0; s < 16; ++s) {
    __syncthreads();  // drains W-async(s) [issued last step] + X loads done
    if (s < 15) {
      stageW(s + 1, (s + 1) & 1);  // drained at next barrier: full-step cover
      loadX(s + 1, (s + 1) & 1);   // ditto
    }
    f16x8 xf[2];
#pragma unroll
    for (int nt = 0; nt < 2; ++nt)
#pragma unroll
      for (int j = 0; j < 8; ++j) xf[nt][j] = (_Float16)xr[s & 1][nt][j];
    const _Float16* pw = &lW[s & 1][0];
    f16x8 wf[4];
#pragma unroll
    for (int ot = 0; ot < 4; ++ot)
      wf[ot] = *(const f16x8*)(pw + ((wo + ot * 16 + lm) * 4 + g) * 8);
    if (mode == 0) {
#pragma unroll
      for (int nt = 0; nt < 2; ++nt)
#pragma unroll
        for (int ot = 0; ot < 4; ++ot)
          acc[nt * 4 + ot] = MFMA16(xf[nt], wf[ot], acc[nt * 4 + ot]);
    } else {
#pragma unroll
      for (int ot = 0; ot < 4; ++ot)
#pragma unroll
        for (int nt = 0; nt < 2; ++nt)
          acc[ot * 2 + nt] = MFMA16(wf[ot], xf[nt], acc[ot * 2 + nt]);
    }
  }

  if (mode == 0) {
#pragma unroll
    for (int nt = 0; nt < 2; ++nt) {
#pragma unroll
      for (int ot = 0; ot < 4; ++ot) {
        int o = wo + ot * 16 + lm;
        float bv_ = bias[o] * bscale;
#pragma unroll
        for (int r = 0; r < 4; ++r) {
          int n = n0 + wn + nt * 16 + g * 4 + r;
          out[((size_t)b * N_ + n) * M + o] =
              (_Float16)(acc[nt * 4 + ot][r] + bv_);
        }
      }
    }
  } else {
#pragma unroll
    for (int ot = 0; ot < 4; ++ot) {
#pragma unroll
      for (int r = 0; r < 4; ++r) {
        int o = o0 + wo + ot * 16 + g * 4 + r;
        float bv_ = bias[o];
#pragma unroll
        for (int nt = 0; nt < 2; ++nt) {
          int n = n0 + wn + nt * 16 + lm;
          out[((size_t)b * M + o) * N_ + n] =
              (_Float16)(acc[ot * 2 + nt][r] + bv_);
        }
      }
    }
  }
}

// ---------------------------------------------------------------------------
// Kernel 3: flash attention, Q-tile 128, split-K x2.
// grid 256 = 4b x 32 q-tiles x 2 key-halves (xcd = bx&7 -> (b,h) per XCD for
// k/v L2 locality). 512 thr / 8 waves; each wave owns a 16-q-row strip for
// S/softmax (wave-local DPP row-max/row-sum -> only 2 barriers/iter) and a
// 64-channel strip x all 128 n for PV (O = 128 VGPRs, AGPR-backed).
// k-tile 32 keys double-buffered in LDS via async16 (issued after T, drained
// at C with S+softmax cover); v frags in registers (issued after C, drained
// at next T with PV cover). launch_bounds (512,2): 256-reg budget, NO spill.
// ---------------------------------------------------------------------------
__global__ __launch_bounds__(512, 2) void attn_kernel(
    const _Float16* __restrict__ qT, const _Float16* __restrict__ kT,
    const _Float16* __restrict__ vT, float* __restrict__ Op0,
    _Float16* __restrict__ Op1, float* __restrict__ mbuf,
    float* __restrict__ lbuf) {
  __shared__ __align__(16) _Float16 kstage[2 * 8192];  // 2 x 16 KB k-tiles
  __shared__ __align__(16) _Float16 P_t[128 * 40];     // P[n][m], pad 40
  __shared__ float al_st[128];
  __shared__ int bumped[8];

  const int tid = threadIdx.x;
  const int lane = tid & 63, wave = tid >> 6;
  const int g = lane >> 4, lm = lane & 15;

  const int bx = blockIdx.x;
  const int xcd = bx & 7;
  const int b = xcd >> 1, h = xcd & 1;
  const int n0 = (bx >> 3) * 128;
  const int mbase = h * 2048;
  const int c0w = wave * 64;

  f32x4 O[4][8];  // [ct][nt]
#pragma unroll
  for (int i = 0; i < 4; ++i)
#pragma unroll
    for (int j = 0; j < 8; ++j) O[i][j] = f32x4{0.f, 0.f, 0.f, 0.f};

  // ---- prologue: q (128 rows x 256 ch) staged in two 64-row rounds ----
  const _Float16* qTb = qT + ((size_t)b * N_ + n0) * CH_;
  f16x8 qf[8];
#pragma unroll
  for (int p = 0; p < 2; ++p) {
#pragma unroll
    for (int r = 0; r < 4; ++r) {
      int sidx = r * 512 + tid;
      int rl = sidx >> 5, cgs = sidx & 31;
      async16(qTb + (size_t)(p * 64 + rl) * CH_ + ((cgs ^ (rl & 7)) * 8),
              (char*)kstage + r * 8192 + wave * 1024);
    }
    __syncthreads();
    if ((wave >> 2) == p) {
      int rl = (wave & 3) * 16 + lm;
#pragma unroll
      for (int ks = 0; ks < 8; ++ks)
        qf[ks] =
            *(const f16x8*)&kstage[rl * 256 + (((ks * 4 + g) ^ (rl & 7)) * 8)];
    }
    __syncthreads();
  }

  const _Float16* kTb = kT + ((size_t)b * N_ + mbase) * CH_;
  auto stage_k = [&](int it) {
    int m0 = it * 32;
    char* dst0 = (char*)kstage + (it & 1) * 16384;
#pragma unroll
    for (int r = 0; r < 2; ++r) {
      int sidx = r * 512 + tid;
      int key = sidx >> 5, cgs = sidx & 31;
      async16(kTb + (size_t)(m0 + key) * CH_ + ((cgs ^ (key & 7)) * 8),
              dst0 + r * 8192 + wave * 1024);
    }
  };
  stage_k(0);

  const _Float16* vTb = vT + (size_t)b * C_ * N_ + mbase;
  const _Float16* vbase[4];
#pragma unroll
  for (int ct = 0; ct < 4; ++ct)
    vbase[ct] = vTb + (size_t)(c0w + ct * 16 + lm) * N_ + g * 8;
  f16x8 vf[4], vfn[4];
#pragma unroll
  for (int ct = 0; ct < 4; ++ct) vf[ct] = *(const f16x8*)vbase[ct];

  f32x4 m_run = f32x4{-1e30f, -1e30f, -1e30f, -1e30f};
  f32x4 l_run = f32x4{0.f, 0.f, 0.f, 0.f};

#pragma unroll 1
  for (int it = 0; it < 64; ++it) {
    __syncthreads();  // T: P_t(it-1) reads done; (it==0) drains stage_k(0)
    if (it < 63) stage_k(it + 1);  // drained at C with S+softmax cover

    // ---- S: wave's 16 rows x 32 keys, K=256 ----
    const _Float16* kb = kstage + (it & 1) * 8192;
    f32x4 s0 = f32x4{0.f, 0.f, 0.f, 0.f};
    f32x4 s1 = f32x4{0.f, 0.f, 0.f, 0.f};
    const int key0 = lm, key1 = 16 + lm;
#pragma unroll
    for (int ks = 0; ks < 8; ++ks) {
      f16x8 kf0 =
          *(const f16x8*)&kb[key0 * 256 + (((ks * 4 + g) ^ (key0 & 7)) * 8)];
      f16x8 kf1 =
          *(const f16x8*)&kb[key1 * 256 + (((ks * 4 + g) ^ (key1 & 7)) * 8)];
      s0 = MFMA16(qf[ks], kf0, s0);
      s1 = MFMA16(qf[ks], kf1, s1);
    }

    // ---- wave-local online softmax (DPP over the 16 key-lanes) ----
    f32x4 alpha;
    bool anyb = false;
#pragma unroll
    for (int r = 0; r < 4; ++r) {
      float mx = rowmax16(fmaxf(s0[r], s1[r]));
      float mnew = fmaxf(m_run[r], mx);
      alpha[r] = exp2f(m_run[r] - mnew);
      anyb |= (mnew > m_run[r]);
      m_run[r] = mnew;
      float p0 = exp2f(s0[r] - mnew);
      float p1 = exp2f(s1[r] - mnew);
      l_run[r] = l_run[r] * alpha[r] + rowsum16(p0 + p1);
      int row = wave * 16 + g * 4 + r;
      P_t[row * 40 + lm] = (_Float16)p0;
      P_t[row * 40 + 16 + lm] = (_Float16)p1;
    }
    if (lm == 0) *(f32x4*)&al_st[wave * 16 + g * 4] = alpha;
    unsigned long long bal = __ballot(anyb);
    if (lane == 0) bumped[wave] = (bal != 0ull) ? 1 : 0;
    __syncthreads();  // C: P_t/al_st visible; drains stage_k(it+1)

    // v prefetch for it+1: drained at next T with full PV cover
    if (it < 63) {
      int mo = (it + 1) * 32;
#pragma unroll
      for (int ct = 0; ct < 4; ++ct)
        vfn[ct] = *(const f16x8*)(vbase[ct] + mo);
    }

    // ---- conditional O-rescale (per row-tile, scalar-branched) ----
#pragma unroll
    for (int nt = 0; nt < 8; ++nt) {
      if (__builtin_amdgcn_readfirstlane(bumped[nt])) {
        float a = al_st[nt * 16 + lm];
#pragma unroll
        for (int ct = 0; ct < 4; ++ct) {
          O[ct][nt][0] *= a; O[ct][nt][1] *= a;
          O[ct][nt][2] *= a; O[ct][nt][3] *= a;
        }
      }
    }

    // ---- PV: O^T[c][n] += v[c][m] * P[n][m] ----
#pragma unroll
    for (int nt = 0; nt < 8; ++nt) {
      f16x8 pf = *(const f16x8*)&P_t[(nt * 16 + lm) * 40 + g * 8];
#pragma unroll
      for (int ct = 0; ct < 4; ++ct) O[ct][nt] = MFMA16(vf[ct], pf, O[ct][nt]);
    }
    if (it < 63) {
#pragma unroll
      for (int ct = 0; ct < 4; ++ct) vf[ct] = vfn[ct];
    }
  }

  // ---- epilogue: partial O + per-row m, l ----
  const size_t hb = (size_t)(b * 2 + h) * N_ + n0;
  if (lm == 0) {
    *(f32x4*)&mbuf[hb + wave * 16 + g * 4] = m_run;
    *(f32x4*)&lbuf[hb + wave * 16 + g * 4] = l_run;
  }
  if (h == 0) {
    float* ob = Op0 + (size_t)b * C_ * N_;
#pragma unroll
    for (int nt = 0; nt < 8; ++nt) {
      int n_g = n0 + nt * 16 + lm;
#pragma unroll
      for (int ct = 0; ct < 4; ++ct) {
        int cb = c0w + ct * 16 + g * 4;
#pragma unroll
        for (int r = 0; r < 4; ++r)
          ob[(size_t)(cb + r) * N_ + n_g] = O[ct][nt][r];
      }
    }
  } else {
    _Float16* ob = Op1 + (size_t)b * C_ * N_;
#pragma unroll
    for (int nt = 0; nt < 8; ++nt) {
      int n_g = n0 + nt * 16 + lm;
#pragma unroll
      for (int ct = 0; ct < 4; ++ct) {
        int cb = c0w + ct * 16 + g * 4;
#pragma unroll
        for (int r = 0; r < 4; ++r)
          ob[(size_t)(cb + r) * N_ + n_g] = (_Float16)O[ct][nt][r];
      }
    }
  }
}

// ---------------------------------------------------------------------------
// Kernel 4: combine the two K-halves + gamma scale + V residual.
// out (= d_out) holds half-0 fp32 partial on entry; Op1 holds half-1 f16.
// out = gamma * (a0*O0 + a1*O1) / (a0*l0 + a1*l1) + V
// ---------------------------------------------------------------------------
__global__ __launch_bounds__(256) void combine_kernel(
    float* __restrict__ out, const _Float16* __restrict__ Op1,
    const float* __restrict__ mbuf, const float* __restrict__ lbuf,
    const float* __restrict__ Vin, const float* __restrict__ gptr) {
  const int b = blockIdx.y;
  const int tid = threadIdx.x;
  const int n = blockIdx.x * 64 + (tid & 15) * 4;
  const int cg = tid >> 4;
  const float gamma = gptr[0];

  float s0[4], s1[4];
#pragma unroll
  for (int j = 0; j < 4; ++j) {
    float m0 = mbuf[(size_t)(b * 2 + 0) * N_ + n + j];
    float m1 = mbuf[(size_t)(b * 2 + 1) * N_ + n + j];
    float mx = fmaxf(m0, m1);
    float a0 = exp2f(m0 - mx), a1 = exp2f(m1 - mx);
    float l = a0 * lbuf[(size_t)(b * 2 + 0) * N_ + n + j] +
              a1 * lbuf[(size_t)(b * 2 + 1) * N_ + n + j];
    float inv = gamma / l;
    s0[j] = a0 * inv;
    s1[j] = a1 * inv;
  }

  const _Float16* O1b = Op1 + (size_t)b * C_ * N_;
  for (int c = cg * 32; c < cg * 32 + 32; ++c) {
    size_t idx = ((size_t)b * C_ + c) * N_ + n;
    f32x4 p0 = *(const f32x4*)(out + idx);
    f16x4 p1 = *(const f16x4*)(O1b + (size_t)c * N_ + n);
    f32x4 V = *(const f32x4*)(Vin + idx);
    f32x4 r;
#pragma unroll
    for (int j = 0; j < 4; ++j)
      r[j] = p0[j] * s0[j] + (float)p1[j] * s1[j] + V[j];
    *(f32x4*)(out + idx) = r;
  }
}

// ---------------------------------------------------------------------------
extern "C" void kernel_launch(void* const* d_in, const int* in_sizes, int n_in,
                              void* d_out, int out_size, void* d_ws, size_t ws_size,
                              hipStream_t stream) {
  const float* Q  = (const float*)d_in[0];
  const float* K  = (const float*)d_in[1];
  const float* V  = (const float*)d_in[2];
  const float* Wq = (const float*)d_in[3];
  const float* bq = (const float*)d_in[4];
  const float* Wk = (const float*)d_in[5];
  const float* bk = (const float*)d_in[6];
  const float* Wv = (const float*)d_in[7];
  const float* bv = (const float*)d_in[8];
  const float* gm = (const float*)d_in[9];
  float* out = (float*)d_out;

  // workspace carve (~42 MB)
  char* p = (char*)d_ws;
  _Float16* wq = (_Float16*)p; p += (size_t)CH_ * C_ * 2;
  _Float16* wk = (_Float16*)p; p += (size_t)CH_ * C_ * 2;
  _Float16* wv = (_Float16*)p; p += (size_t)C_ * C_ * 2;
  _Float16* qT = (_Float16*)p; p += (size_t)B_ * N_ * CH_ * 2;
  _Float16* kT = (_Float16*)p; p += (size_t)B_ * N_ * CH_ * 2;
  _Float16* vT = (_Float16*)p; p += (size_t)B_ * C_ * N_ * 2;
  _Float16* Op1 = (_Float16*)p; p += (size_t)B_ * C_ * N_ * 2;  // half-1 partial
  float* mbuf = (float*)p; p += (size_t)B_ * 2 * N_ * 4;
  float* lbuf = (float*)p; p += (size_t)B_ * 2 * N_ * 4;

  prep_w_kernel<<<(C_ * C_) / 256, 256, 0, stream>>>(Wq, Wk, Wv, wq, wk, wv);

  // fused q/k/v projections (y: 0=q, 1=k, 2,3=v halves)
  proj_kernel<<<dim3(N_ / 64, 4, B_), 512, 0, stream>>>(
      wq, wk, wv, Q, K, V, bq, bk, bv, qT, kT, vT);

  // split-K flash attention: half-0 partial -> d_out (fp32), half-1 -> Op1
  attn_kernel<<<256, 512, 0, stream>>>(qT, kT, vT, out, Op1, mbuf, lbuf);

  combine_kernel<<<dim3(N_ / 64, B_), 256, 0, stream>>>(out, Op1, mbuf, lbuf,
                                                        V, gm);
}

// Round 6
// 399.969 us; speedup vs baseline: 2.5484x; 1.0039x over previous
//
#include <hip/hip_runtime.h>
#include <cstdint>
#include <cstddef>

// Problem constants
constexpr int B_  = 4;
constexpr int C_  = 512;
constexpr int CH_ = 256;
constexpr int N_  = 4096;
#define LOG2E 1.4426950408889634f

typedef float    f32x4 __attribute__((ext_vector_type(4)));
typedef _Float16 f16x8 __attribute__((ext_vector_type(8)));
typedef _Float16 f16x4 __attribute__((ext_vector_type(4)));

__device__ __forceinline__ f32x4 MFMA16(f16x8 a, f16x8 b, f32x4 c) {
  return __builtin_amdgcn_mfma_f32_16x16x32_f16(a, b, c, 0, 0, 0);
}

// async global->LDS, 16B per lane; LDS dest is wave-uniform base + lane*16
typedef const __attribute__((address_space(1))) unsigned int* gas_u32p;
typedef __attribute__((address_space(3))) unsigned int* las_u32p;
__device__ __forceinline__ void async16(const void* g, void* l) {
  __builtin_amdgcn_global_load_lds((gas_u32p)g, (las_u32p)l, 16, 0, 0);
}

// DPP 16-lane max reduction (row_ror 8/4/2/1) — VALU only
template <int CTRL>
__device__ __forceinline__ float dppmax(float x) {
  float y = __builtin_bit_cast(
      float, __builtin_amdgcn_update_dpp(0, __builtin_bit_cast(int, x), CTRL,
                                         0xF, 0xF, true));
  return fmaxf(x, y);
}
__device__ __forceinline__ float rowmax16(float x) {
  x = dppmax<0x128>(x); x = dppmax<0x124>(x);
  x = dppmax<0x122>(x); x = dppmax<0x121>(x);
  return x;
}

// ---------------------------------------------------------------------------
// Kernel 1: weight prep -> fp16. Wq scaled by LOG2E (softmax in exp2 domain).
// ---------------------------------------------------------------------------
__global__ void prep_w_kernel(const float* __restrict__ Wq,
                              const float* __restrict__ Wk,
                              const float* __restrict__ Wv,
                              _Float16* __restrict__ wq,
                              _Float16* __restrict__ wk,
                              _Float16* __restrict__ wv) {
  int i = blockIdx.x * 256 + threadIdx.x;
  if (i < CH_ * C_) {
    wq[i] = (_Float16)(Wq[i] * LOG2E);
    wk[i] = (_Float16)Wk[i];
  }
  if (i < C_ * C_) wv[i] = (_Float16)Wv[i];
}

// ---------------------------------------------------------------------------
// Kernel 2: fused projection GEMM (q, k, v in one launch; blockIdx.y selects).
// R4-proven structure. W fp16 via async16 (double-buffered); X fp32 prefetched
// one K-step ahead into registers. (512,4): ~120 VGPR fits the 128 cap ->
// 2 blocks/CU co-resident to hide the strided-X HBM latency via TLP.
// ---------------------------------------------------------------------------
__global__ __launch_bounds__(512, 4) void proj_kernel(
    const _Float16* __restrict__ wq, const _Float16* __restrict__ wk,
    const _Float16* __restrict__ wv, const float* __restrict__ Q,
    const float* __restrict__ K, const float* __restrict__ V,
    const float* __restrict__ bq, const float* __restrict__ bk,
    const float* __restrict__ bv, _Float16* __restrict__ qT,
    _Float16* __restrict__ kT, _Float16* __restrict__ vT) {
  __shared__ __align__(16) _Float16 lW[2][256 * 32];  // 16 KB per buf

  const int y = blockIdx.y;
  const _Float16* W;
  const float* X;
  const float* bias;
  _Float16* out;
  int o0 = 0, M, mode;
  float bscale = 1.0f;
  if (y == 0) {
    W = wq; X = Q; bias = bq; out = qT; M = CH_; mode = 0; bscale = LOG2E;
  } else if (y == 1) {
    W = wk; X = K; bias = bk; out = kT; M = CH_; mode = 0;
  } else {
    W = wv; X = V; bias = bv; out = vT; M = C_; mode = 1; o0 = (y - 2) * 256;
  }

  const int tid = threadIdx.x;
  const int lane = tid & 63, wave = tid >> 6;
  const int g = lane >> 4, lm = lane & 15;
  const int b = blockIdx.z;
  const int n0 = blockIdx.x * 64;
  const int wo = (wave >> 1) * 64, wn = (wave & 1) * 32;

  const _Float16* Wb = W + (size_t)o0 * C_;
  const float* Xb = X + (size_t)b * C_ * N_;
  const int ncol = n0 + wn + lm;

  f32x4 acc[8];
#pragma unroll
  for (int i = 0; i < 8; ++i) acc[i] = f32x4{0.f, 0.f, 0.f, 0.f};

  auto stageW = [&](int s, int buf) {
    int c0 = s * 32;
#pragma unroll
    for (int r = 0; r < 2; ++r) {
      int ci = r * 512 + tid;
      int o = ci >> 2, cg = ci & 3;
      async16(Wb + (size_t)o * C_ + c0 + cg * 8,
              (char*)&lW[buf][0] + r * 8192 + wave * 1024);
    }
  };

  float xr[2][2][8];  // X prefetch double-buffer (registers)
  auto loadX = [&](int s, int buf) {
    int c0 = s * 32;
#pragma unroll
    for (int nt = 0; nt < 2; ++nt) {
      const float* xp = Xb + (size_t)(c0 + g * 8) * N_ + ncol + nt * 16;
#pragma unroll
      for (int j = 0; j < 8; ++j) xr[buf][nt][j] = xp[(size_t)j * N_];
    }
  };

  stageW(0, 0);
  loadX(0, 0);

#pragma unroll
  for (int s = 0; s < 16; ++s) {
    __syncthreads();  // drains W-async(s) + X loads(s) issued last step
    if (s < 15) {
      stageW(s + 1, (s + 1) & 1);  // drained at next barrier: full-step cover
      loadX(s + 1, (s + 1) & 1);   // ditto
    }
    f16x8 xf[2];
#pragma unroll
    for (int nt = 0; nt < 2; ++nt)
#pragma unroll
      for (int j = 0; j < 8; ++j) xf[nt][j] = (_Float16)xr[s & 1][nt][j];
    const _Float16* pw = &lW[s & 1][0];
    f16x8 wf[4];
#pragma unroll
    for (int ot = 0; ot < 4; ++ot)
      wf[ot] = *(const f16x8*)(pw + ((wo + ot * 16 + lm) * 4 + g) * 8);
    if (mode == 0) {
#pragma unroll
      for (int nt = 0; nt < 2; ++nt)
#pragma unroll
        for (int ot = 0; ot < 4; ++ot)
          acc[nt * 4 + ot] = MFMA16(xf[nt], wf[ot], acc[nt * 4 + ot]);
    } else {
#pragma unroll
      for (int ot = 0; ot < 4; ++ot)
#pragma unroll
        for (int nt = 0; nt < 2; ++nt)
          acc[ot * 2 + nt] = MFMA16(wf[ot], xf[nt], acc[ot * 2 + nt]);
    }
  }

  if (mode == 0) {
#pragma unroll
    for (int nt = 0; nt < 2; ++nt) {
#pragma unroll
      for (int ot = 0; ot < 4; ++ot) {
        int o = wo + ot * 16 + lm;
        float bv_ = bias[o] * bscale;
#pragma unroll
        for (int r = 0; r < 4; ++r) {
          int n = n0 + wn + nt * 16 + g * 4 + r;
          out[((size_t)b * N_ + n) * M + o] =
              (_Float16)(acc[nt * 4 + ot][r] + bv_);
        }
      }
    }
  } else {
#pragma unroll
    for (int ot = 0; ot < 4; ++ot) {
#pragma unroll
      for (int r = 0; r < 4; ++r) {
        int o = o0 + wo + ot * 16 + g * 4 + r;
        float bv_ = bias[o];
#pragma unroll
        for (int nt = 0; nt < 2; ++nt) {
          int n = n0 + wn + nt * 16 + lm;
          out[((size_t)b * M + o) * N_ + n] =
              (_Float16)(acc[ot * 2 + nt][r] + bv_);
        }
      }
    }
  }
}

// ---------------------------------------------------------------------------
// Kernel 3: flash attention, Q-tile 128, split-K x2 — R4-proven 2-barrier
// structure. Deltas vs R4: (1) P_t stride 40 -> 72 halves (144B rows: PV
// b128 P-reads become <=2-way bank pattern); (2) l via ones-row MFMA
// (replaces 32-op DPP rowsum chain), rescaled with alpha like O.
// ---------------------------------------------------------------------------
__global__ __launch_bounds__(512, 2) void attn_kernel(
    const _Float16* __restrict__ qT, const _Float16* __restrict__ kT,
    const _Float16* __restrict__ vT, float* __restrict__ Op0,
    _Float16* __restrict__ Op1, float* __restrict__ mbuf,
    float* __restrict__ lbuf) {
  __shared__ __align__(16) _Float16 kstage[2 * 8192];  // 2 x 16 KB k-tiles
  __shared__ __align__(16) _Float16 P_t[128 * 72];     // P[n][m], stride 72
  __shared__ float al_st[128];
  __shared__ int bumped[8];

  const int tid = threadIdx.x;
  const int lane = tid & 63, wave = tid >> 6;
  const int g = lane >> 4, lm = lane & 15;

  const int bx = blockIdx.x;
  const int xcd = bx & 7;
  const int b = xcd >> 1, h = xcd & 1;
  const int n0 = (bx >> 3) * 128;
  const int mbase = h * 2048;
  const int c0w = wave * 64;

  f32x4 O[4][8];  // [ct][nt]
#pragma unroll
  for (int i = 0; i < 4; ++i)
#pragma unroll
    for (int j = 0; j < 8; ++j) O[i][j] = f32x4{0.f, 0.f, 0.f, 0.f};
  f32x4 Ol = f32x4{0.f, 0.f, 0.f, 0.f};  // l accumulator (ones-MFMA)

  // ---- prologue: q (128 rows x 256 ch) staged in two 64-row rounds ----
  const _Float16* qTb = qT + ((size_t)b * N_ + n0) * CH_;
  f16x8 qf[8];
#pragma unroll
  for (int p = 0; p < 2; ++p) {
#pragma unroll
    for (int r = 0; r < 4; ++r) {
      int sidx = r * 512 + tid;
      int rl = sidx >> 5, cgs = sidx & 31;
      async16(qTb + (size_t)(p * 64 + rl) * CH_ + ((cgs ^ (rl & 7)) * 8),
              (char*)kstage + r * 8192 + wave * 1024);
    }
    __syncthreads();
    if ((wave >> 2) == p) {
      int rl = (wave & 3) * 16 + lm;
#pragma unroll
      for (int ks = 0; ks < 8; ++ks)
        qf[ks] =
            *(const f16x8*)&kstage[rl * 256 + (((ks * 4 + g) ^ (rl & 7)) * 8)];
    }
    __syncthreads();
  }

  const _Float16* kTb = kT + ((size_t)b * N_ + mbase) * CH_;
  auto stage_k = [&](int it) {
    int m0 = it * 32;
    char* dst0 = (char*)kstage + (it & 1) * 16384;
#pragma unroll
    for (int r = 0; r < 2; ++r) {
      int sidx = r * 512 + tid;
      int key = sidx >> 5, cgs = sidx & 31;
      async16(kTb + (size_t)(m0 + key) * CH_ + ((cgs ^ (key & 7)) * 8),
              dst0 + r * 8192 + wave * 1024);
    }
  };
  stage_k(0);

  const _Float16* vTb = vT + (size_t)b * C_ * N_ + mbase;
  const _Float16* vbase[4];
#pragma unroll
  for (int ct = 0; ct < 4; ++ct)
    vbase[ct] = vTb + (size_t)(c0w + ct * 16 + lm) * N_ + g * 8;
  f16x8 vf[4], vfn[4];
#pragma unroll
  for (int ct = 0; ct < 4; ++ct) vf[ct] = *(const f16x8*)vbase[ct];

  f32x4 m_run = f32x4{-1e30f, -1e30f, -1e30f, -1e30f};
  f16x8 ones;
#pragma unroll
  for (int i = 0; i < 8; ++i) ones[i] = (_Float16)1.0f;

#pragma unroll 1
  for (int it = 0; it < 64; ++it) {
    __syncthreads();  // T: P_t(it-1) reads done; (it==0) drains stage_k(0)
    if (it < 63) stage_k(it + 1);  // drained at C with S+softmax cover

    // ---- S: wave's 16 rows x 32 keys, K=256 ----
    const _Float16* kb = kstage + (it & 1) * 8192;
    f32x4 s0 = f32x4{0.f, 0.f, 0.f, 0.f};
    f32x4 s1 = f32x4{0.f, 0.f, 0.f, 0.f};
    const int key0 = lm, key1 = 16 + lm;
#pragma unroll
    for (int ks = 0; ks < 8; ++ks) {
      f16x8 kf0 =
          *(const f16x8*)&kb[key0 * 256 + (((ks * 4 + g) ^ (key0 & 7)) * 8)];
      f16x8 kf1 =
          *(const f16x8*)&kb[key1 * 256 + (((ks * 4 + g) ^ (key1 & 7)) * 8)];
      s0 = MFMA16(qf[ks], kf0, s0);
      s1 = MFMA16(qf[ks], kf1, s1);
    }

    // ---- wave-local online softmax (DPP rowmax; l comes from ones-MFMA) ----
    f32x4 alpha;
    bool anyb = false;
#pragma unroll
    for (int r = 0; r < 4; ++r) {
      float mx = rowmax16(fmaxf(s0[r], s1[r]));
      float mnew = fmaxf(m_run[r], mx);
      alpha[r] = exp2f(m_run[r] - mnew);
      anyb |= (mnew > m_run[r]);
      m_run[r] = mnew;
      float p0 = exp2f(s0[r] - mnew);
      float p1 = exp2f(s1[r] - mnew);
      int row = wave * 16 + g * 4 + r;
      P_t[row * 72 + lm] = (_Float16)p0;
      P_t[row * 72 + 16 + lm] = (_Float16)p1;
    }
    if (lm == 0) *(f32x4*)&al_st[wave * 16 + g * 4] = alpha;
    unsigned long long bal = __ballot(anyb);
    if (lane == 0) bumped[wave] = (bal != 0ull) ? 1 : 0;
    __syncthreads();  // C: P_t/al_st/bumped visible; drains stage_k(it+1)

    // v prefetch for it+1: drained at next T with rescale+PV cover
    if (it < 63) {
      int mo = (it + 1) * 32;
#pragma unroll
      for (int ct = 0; ct < 4; ++ct)
        vfn[ct] = *(const f16x8*)(vbase[ct] + mo);
    }

    // ---- conditional O-rescale (per row-strip, scalar-branched) ----
#pragma unroll
    for (int nt = 0; nt < 8; ++nt) {
      if (__builtin_amdgcn_readfirstlane(bumped[nt])) {
        float a = al_st[nt * 16 + lm];
#pragma unroll
        for (int ct = 0; ct < 4; ++ct) {
          O[ct][nt][0] *= a; O[ct][nt][1] *= a;
          O[ct][nt][2] *= a; O[ct][nt][3] *= a;
        }
      }
    }
    if (__builtin_amdgcn_readfirstlane(bumped[wave])) {
      float a = al_st[wave * 16 + lm];
      Ol[0] *= a; Ol[1] *= a; Ol[2] *= a; Ol[3] *= a;
    }

    // ---- PV: O^T[c][n] += v[c][m] * P[n][m] ----
#pragma unroll
    for (int nt = 0; nt < 8; ++nt) {
      f16x8 pf = *(const f16x8*)&P_t[(nt * 16 + lm) * 72 + g * 8];
#pragma unroll
      for (int ct = 0; ct < 4; ++ct) O[ct][nt] = MFMA16(vf[ct], pf, O[ct][nt]);
    }
    {  // l for this wave's own 16 rows: D[m][n] = sum_k P[wave*16+n][k]
      f16x8 pfo = *(const f16x8*)&P_t[(wave * 16 + lm) * 72 + g * 8];
      Ol = MFMA16(ones, pfo, Ol);
    }
    if (it < 63) {
#pragma unroll
      for (int ct = 0; ct < 4; ++ct) vf[ct] = vfn[ct];
    }
  }

  // ---- epilogue: partial O + per-row m, l ----
  const size_t hb = (size_t)(b * 2 + h) * N_ + n0;
  if (lm == 0) {
#pragma unroll
    for (int r = 0; r < 4; ++r) mbuf[hb + wave * 16 + g * 4 + r] = m_run[r];
  }
  if (lane < 16) lbuf[hb + wave * 16 + lane] = Ol[0];

  if (h == 0) {
    float* ob = Op0 + (size_t)b * C_ * N_;
#pragma unroll
    for (int nt = 0; nt < 8; ++nt) {
      int n_g = n0 + nt * 16 + lm;
#pragma unroll
      for (int ct = 0; ct < 4; ++ct) {
        int cb = c0w + ct * 16 + g * 4;
#pragma unroll
        for (int r = 0; r < 4; ++r)
          ob[(size_t)(cb + r) * N_ + n_g] = O[ct][nt][r];
      }
    }
  } else {
    _Float16* ob = Op1 + (size_t)b * C_ * N_;
#pragma unroll
    for (int nt = 0; nt < 8; ++nt) {
      int n_g = n0 + nt * 16 + lm;
#pragma unroll
      for (int ct = 0; ct < 4; ++ct) {
        int cb = c0w + ct * 16 + g * 4;
#pragma unroll
        for (int r = 0; r < 4; ++r)
          ob[(size_t)(cb + r) * N_ + n_g] = (_Float16)O[ct][nt][r];
      }
    }
  }
}

// ---------------------------------------------------------------------------
// Kernel 4: combine the two K-halves + gamma scale + V residual.
// out = gamma * (a0*O0 + a1*O1) / (a0*l0 + a1*l1) + V
// ---------------------------------------------------------------------------
__global__ __launch_bounds__(256) void combine_kernel(
    float* __restrict__ out, const _Float16* __restrict__ Op1,
    const float* __restrict__ mbuf, const float* __restrict__ lbuf,
    const float* __restrict__ Vin, const float* __restrict__ gptr) {
  const int b = blockIdx.y;
  const int tid = threadIdx.x;
  const int n = blockIdx.x * 64 + (tid & 15) * 4;
  const int cg = tid >> 4;
  const float gamma = gptr[0];

  float s0[4], s1[4];
#pragma unroll
  for (int j = 0; j < 4; ++j) {
    float m0 = mbuf[(size_t)(b * 2 + 0) * N_ + n + j];
    float m1 = mbuf[(size_t)(b * 2 + 1) * N_ + n + j];
    float mx = fmaxf(m0, m1);
    float a0 = exp2f(m0 - mx), a1 = exp2f(m1 - mx);
    float l = a0 * lbuf[(size_t)(b * 2 + 0) * N_ + n + j] +
              a1 * lbuf[(size_t)(b * 2 + 1) * N_ + n + j];
    float inv = gamma / l;
    s0[j] = a0 * inv;
    s1[j] = a1 * inv;
  }

  const _Float16* O1b = Op1 + (size_t)b * C_ * N_;
  for (int c = cg * 32; c < cg * 32 + 32; ++c) {
    size_t idx = ((size_t)b * C_ + c) * N_ + n;
    f32x4 p0 = *(const f32x4*)(out + idx);
    f16x4 p1 = *(const f16x4*)(O1b + (size_t)c * N_ + n);
    f32x4 V = *(const f32x4*)(Vin + idx);
    f32x4 r;
#pragma unroll
    for (int j = 0; j < 4; ++j)
      r[j] = p0[j] * s0[j] + (float)p1[j] * s1[j] + V[j];
    *(f32x4*)(out + idx) = r;
  }
}

// ---------------------------------------------------------------------------
extern "C" void kernel_launch(void* const* d_in, const int* in_sizes, int n_in,
                              void* d_out, int out_size, void* d_ws, size_t ws_size,
                              hipStream_t stream) {
  const float* Q  = (const float*)d_in[0];
  const float* K  = (const float*)d_in[1];
  const float* V  = (const float*)d_in[2];
  const float* Wq = (const float*)d_in[3];
  const float* bq = (const float*)d_in[4];
  const float* Wk = (const float*)d_in[5];
  const float* bk = (const float*)d_in[6];
  const float* Wv = (const float*)d_in[7];
  const float* bv = (const float*)d_in[8];
  const float* gm = (const float*)d_in[9];
  float* out = (float*)d_out;

  // workspace carve (~42 MB)
  char* p = (char*)d_ws;
  _Float16* wq = (_Float16*)p; p += (size_t)CH_ * C_ * 2;
  _Float16* wk = (_Float16*)p; p += (size_t)CH_ * C_ * 2;
  _Float16* wv = (_Float16*)p; p += (size_t)C_ * C_ * 2;
  _Float16* qT = (_Float16*)p; p += (size_t)B_ * N_ * CH_ * 2;
  _Float16* kT = (_Float16*)p; p += (size_t)B_ * N_ * CH_ * 2;
  _Float16* vT = (_Float16*)p; p += (size_t)B_ * C_ * N_ * 2;
  _Float16* Op1 = (_Float16*)p; p += (size_t)B_ * C_ * N_ * 2;  // half-1 partial
  float* mbuf = (float*)p; p += (size_t)B_ * 2 * N_ * 4;
  float* lbuf = (float*)p; p += (size_t)B_ * 2 * N_ * 4;

  prep_w_kernel<<<(C_ * C_) / 256, 256, 0, stream>>>(Wq, Wk, Wv, wq, wk, wv);

  // fused q/k/v projections (y: 0=q, 1=k, 2,3=v halves)
  proj_kernel<<<dim3(N_ / 64, 4, B_), 512, 0, stream>>>(
      wq, wk, wv, Q, K, V, bq, bk, bv, qT, kT, vT);

  // split-K flash attention: half-0 partial -> d_out (fp32), half-1 -> Op1
  attn_kernel<<<256, 512, 0, stream>>>(qT, kT, vT, out, Op1, mbuf, lbuf);

  combine_kernel<<<dim3(N_ / 64, B_), 256, 0, stream>>>(out, Op1, mbuf, lbuf,
                                                        V, gm);
}

// Round 7
// 376.704 us; speedup vs baseline: 2.7058x; 1.0618x over previous
//
#include <hip/hip_runtime.h>
#include <cstdint>
#include <cstddef>

// Problem constants
constexpr int B_  = 4;
constexpr int C_  = 512;
constexpr int CH_ = 256;
constexpr int N_  = 4096;
#define LOG2E 1.4426950408889634f

typedef float    f32x4 __attribute__((ext_vector_type(4)));
typedef _Float16 f16x8 __attribute__((ext_vector_type(8)));
typedef _Float16 f16x4 __attribute__((ext_vector_type(4)));

__device__ __forceinline__ f32x4 MFMA16(f16x8 a, f16x8 b, f32x4 c) {
  return __builtin_amdgcn_mfma_f32_16x16x32_f16(a, b, c, 0, 0, 0);
}

// async global->LDS, 16B per lane; LDS dest is wave-uniform base + lane*16
typedef const __attribute__((address_space(1))) unsigned int* gas_u32p;
typedef __attribute__((address_space(3))) unsigned int* las_u32p;
__device__ __forceinline__ void async16(const void* g, void* l) {
  __builtin_amdgcn_global_load_lds((gas_u32p)g, (las_u32p)l, 16, 0, 0);
}

// DPP 16-lane max reduction (row_ror 8/4/2/1) — VALU only
template <int CTRL>
__device__ __forceinline__ float dppmax(float x) {
  float y = __builtin_bit_cast(
      float, __builtin_amdgcn_update_dpp(0, __builtin_bit_cast(int, x), CTRL,
                                         0xF, 0xF, true));
  return fmaxf(x, y);
}
__device__ __forceinline__ float rowmax16(float x) {
  x = dppmax<0x128>(x); x = dppmax<0x124>(x);
  x = dppmax<0x122>(x); x = dppmax<0x121>(x);
  return x;
}

// ---------------------------------------------------------------------------
// Kernel 1: weight prep -> fp16. Wq scaled by LOG2E (softmax in exp2 domain).
// ---------------------------------------------------------------------------
__global__ void prep_w_kernel(const float* __restrict__ Wq,
                              const float* __restrict__ Wk,
                              const float* __restrict__ Wv,
                              _Float16* __restrict__ wq,
                              _Float16* __restrict__ wk,
                              _Float16* __restrict__ wv) {
  int i = blockIdx.x * 256 + threadIdx.x;
  if (i < CH_ * C_) {
    wq[i] = (_Float16)(Wq[i] * LOG2E);
    wk[i] = (_Float16)Wk[i];
  }
  if (i < C_ * C_) wv[i] = (_Float16)Wv[i];
}

// ---------------------------------------------------------------------------
// Kernel 2: fused projection GEMM (q, k, v in one launch; blockIdx.y selects).
//   out[o][n] = sum_c W[o][c] * X[c][n] + bias[o]
// NEW X-path (the R3-R6 versions used per-lane stride-N scalar loads with
// ~40cyc cover -> latency-bound): X tile (32c x 64n) loaded as ONE coalesced
// f32x4 per thread, transposed in-LDS to [n][c] (stride 56 halves, c-granule
// XOR by (n>>2)&3 to spread the scatter-write banks), 3-deep register
// pipeline: load(s+2) in flight, write(s+1) under full-step cover, consume(s).
// One barrier per step. W keeps the R6 async16 double-buffer. ~90 VGPR ->
// (512,4): 2 blocks/CU so barrier drains overlap the other block's compute.
// ---------------------------------------------------------------------------
__global__ __launch_bounds__(512, 4) void proj_kernel(
    const _Float16* __restrict__ wq, const _Float16* __restrict__ wk,
    const _Float16* __restrict__ wv, const float* __restrict__ Q,
    const float* __restrict__ K, const float* __restrict__ V,
    const float* __restrict__ bq, const float* __restrict__ bk,
    const float* __restrict__ bv, _Float16* __restrict__ qT,
    _Float16* __restrict__ kT, _Float16* __restrict__ vT) {
  __shared__ __align__(16) _Float16 lW[2][256 * 32];  // 16 KB per buf
  __shared__ __align__(16) _Float16 lX[2][64 * 56];   // [n][c] swizzled, 7 KB

  const int y = blockIdx.y;
  const _Float16* W;
  const float* X;
  const float* bias;
  _Float16* out;
  int o0 = 0, M, mode;
  float bscale = 1.0f;
  if (y == 0) {
    W = wq; X = Q; bias = bq; out = qT; M = CH_; mode = 0; bscale = LOG2E;
  } else if (y == 1) {
    W = wk; X = K; bias = bk; out = kT; M = CH_; mode = 0;
  } else {
    W = wv; X = V; bias = bv; out = vT; M = C_; mode = 1; o0 = (y - 2) * 256;
  }

  const int tid = threadIdx.x;
  const int lane = tid & 63, wave = tid >> 6;
  const int g = lane >> 4, lm = lane & 15;
  const int b = blockIdx.z;
  const int n0 = blockIdx.x * 64;
  const int wo = (wave >> 1) * 64, wn = (wave & 1) * 32;

  const _Float16* Wb = W + (size_t)o0 * C_;
  const float* Xb = X + (size_t)b * C_ * N_;

  f32x4 acc[8];
#pragma unroll
  for (int i = 0; i < 8; ++i) acc[i] = f32x4{0.f, 0.f, 0.f, 0.f};

  auto stageW = [&](int s, int buf) {
    int c0 = s * 32;
#pragma unroll
    for (int r = 0; r < 2; ++r) {
      int ci = r * 512 + tid;
      int o = ci >> 2, cg = ci & 3;
      async16(Wb + (size_t)o * C_ + c0 + cg * 8,
              (char*)&lW[buf][0] + r * 8192 + wave * 1024);
    }
  };

  // X: thread (xc = c-row 0..31, xn4 = 4 consecutive n) — coalesced f32x4.
  const int xc = tid >> 4;
  const int xn4 = (tid & 15) * 4;
  const int xgran = xc >> 3, xcin = xc & 7;
  auto gloadX = [&](int s) {
    return *(const f32x4*)(Xb + (size_t)(s * 32 + xc) * N_ + n0 + xn4);
  };
  auto writeX = [&](int buf, f32x4 v) {
#pragma unroll
    for (int i = 0; i < 4; ++i) {
      int n = xn4 + i;
      int pos = (xgran ^ ((n >> 2) & 3)) * 8 + xcin;
      lX[buf][n * 56 + pos] = (_Float16)v[i];
    }
  };

  // prologue: fill buf0 X, issue W(0), preload X(1)
  f32x4 xg = gloadX(0);
  writeX(0, xg);
  xg = gloadX(1);
  stageW(0, 0);
  __syncthreads();

#pragma unroll
  for (int s = 0; s < 16; ++s) {
    const int cb = s & 1, nb = cb ^ 1;
    if (s < 15) stageW(s + 1, nb);
    f32x4 xgn;
    if (s < 14) xgn = gloadX(s + 2);

    f16x8 wf[4], xf[2];
#pragma unroll
    for (int ot = 0; ot < 4; ++ot)
      wf[ot] = *(const f16x8*)&lW[cb][((wo + ot * 16 + lm) * 4 + g) * 8];
#pragma unroll
    for (int nt = 0; nt < 2; ++nt) {
      int n = wn + nt * 16 + lm;
      int pos = (g ^ ((n >> 2) & 3)) * 8;
      xf[nt] = *(const f16x8*)&lX[cb][n * 56 + pos];
    }

    if (mode == 0) {
#pragma unroll
      for (int nt = 0; nt < 2; ++nt)
#pragma unroll
        for (int ot = 0; ot < 4; ++ot)
          acc[nt * 4 + ot] = MFMA16(xf[nt], wf[ot], acc[nt * 4 + ot]);
    } else {
#pragma unroll
      for (int ot = 0; ot < 4; ++ot)
#pragma unroll
        for (int nt = 0; nt < 2; ++nt)
          acc[ot * 2 + nt] = MFMA16(wf[ot], xf[nt], acc[ot * 2 + nt]);
    }

    if (s < 15) writeX(nb, xg);  // X(s+1) -> LDS, cover = this step's MFMAs
    if (s < 14) xg = xgn;
    __syncthreads();  // drains stageW(s+1)+gloadX(s+2); writeX visible
  }

  if (mode == 0) {
#pragma unroll
    for (int nt = 0; nt < 2; ++nt) {
#pragma unroll
      for (int ot = 0; ot < 4; ++ot) {
        int o = wo + ot * 16 + lm;
        float bv_ = bias[o] * bscale;
#pragma unroll
        for (int r = 0; r < 4; ++r) {
          int n = n0 + wn + nt * 16 + g * 4 + r;
          out[((size_t)b * N_ + n) * M + o] =
              (_Float16)(acc[nt * 4 + ot][r] + bv_);
        }
      }
    }
  } else {
#pragma unroll
    for (int ot = 0; ot < 4; ++ot) {
#pragma unroll
      for (int r = 0; r < 4; ++r) {
        int o = o0 + wo + ot * 16 + g * 4 + r;
        float bv_ = bias[o];
#pragma unroll
        for (int nt = 0; nt < 2; ++nt) {
          int n = n0 + wn + nt * 16 + lm;
          out[((size_t)b * M + o) * N_ + n] =
              (_Float16)(acc[ot * 2 + nt][r] + bv_);
        }
      }
    }
  }
}

// ---------------------------------------------------------------------------
// Kernel 3: flash attention, Q-tile 128, split-K x2 — R6 version, unchanged.
// ---------------------------------------------------------------------------
__global__ __launch_bounds__(512, 2) void attn_kernel(
    const _Float16* __restrict__ qT, const _Float16* __restrict__ kT,
    const _Float16* __restrict__ vT, float* __restrict__ Op0,
    _Float16* __restrict__ Op1, float* __restrict__ mbuf,
    float* __restrict__ lbuf) {
  __shared__ __align__(16) _Float16 kstage[2 * 8192];  // 2 x 16 KB k-tiles
  __shared__ __align__(16) _Float16 P_t[128 * 72];     // P[n][m], stride 72
  __shared__ float al_st[128];
  __shared__ int bumped[8];

  const int tid = threadIdx.x;
  const int lane = tid & 63, wave = tid >> 6;
  const int g = lane >> 4, lm = lane & 15;

  const int bx = blockIdx.x;
  const int xcd = bx & 7;
  const int b = xcd >> 1, h = xcd & 1;
  const int n0 = (bx >> 3) * 128;
  const int mbase = h * 2048;
  const int c0w = wave * 64;

  f32x4 O[4][8];  // [ct][nt]
#pragma unroll
  for (int i = 0; i < 4; ++i)
#pragma unroll
    for (int j = 0; j < 8; ++j) O[i][j] = f32x4{0.f, 0.f, 0.f, 0.f};
  f32x4 Ol = f32x4{0.f, 0.f, 0.f, 0.f};  // l accumulator (ones-MFMA)

  // ---- prologue: q (128 rows x 256 ch) staged in two 64-row rounds ----
  const _Float16* qTb = qT + ((size_t)b * N_ + n0) * CH_;
  f16x8 qf[8];
#pragma unroll
  for (int p = 0; p < 2; ++p) {
#pragma unroll
    for (int r = 0; r < 4; ++r) {
      int sidx = r * 512 + tid;
      int rl = sidx >> 5, cgs = sidx & 31;
      async16(qTb + (size_t)(p * 64 + rl) * CH_ + ((cgs ^ (rl & 7)) * 8),
              (char*)kstage + r * 8192 + wave * 1024);
    }
    __syncthreads();
    if ((wave >> 2) == p) {
      int rl = (wave & 3) * 16 + lm;
#pragma unroll
      for (int ks = 0; ks < 8; ++ks)
        qf[ks] =
            *(const f16x8*)&kstage[rl * 256 + (((ks * 4 + g) ^ (rl & 7)) * 8)];
    }
    __syncthreads();
  }

  const _Float16* kTb = kT + ((size_t)b * N_ + mbase) * CH_;
  auto stage_k = [&](int it) {
    int m0 = it * 32;
    char* dst0 = (char*)kstage + (it & 1) * 16384;
#pragma unroll
    for (int r = 0; r < 2; ++r) {
      int sidx = r * 512 + tid;
      int key = sidx >> 5, cgs = sidx & 31;
      async16(kTb + (size_t)(m0 + key) * CH_ + ((cgs ^ (key & 7)) * 8),
              dst0 + r * 8192 + wave * 1024);
    }
  };
  stage_k(0);

  const _Float16* vTb = vT + (size_t)b * C_ * N_ + mbase;
  const _Float16* vbase[4];
#pragma unroll
  for (int ct = 0; ct < 4; ++ct)
    vbase[ct] = vTb + (size_t)(c0w + ct * 16 + lm) * N_ + g * 8;
  f16x8 vf[4], vfn[4];
#pragma unroll
  for (int ct = 0; ct < 4; ++ct) vf[ct] = *(const f16x8*)vbase[ct];

  f32x4 m_run = f32x4{-1e30f, -1e30f, -1e30f, -1e30f};
  f16x8 ones;
#pragma unroll
  for (int i = 0; i < 8; ++i) ones[i] = (_Float16)1.0f;

#pragma unroll 1
  for (int it = 0; it < 64; ++it) {
    __syncthreads();  // T: P_t(it-1) reads done; (it==0) drains stage_k(0)
    if (it < 63) stage_k(it + 1);  // drained at C with S+softmax cover

    // ---- S: wave's 16 rows x 32 keys, K=256 ----
    const _Float16* kb = kstage + (it & 1) * 8192;
    f32x4 s0 = f32x4{0.f, 0.f, 0.f, 0.f};
    f32x4 s1 = f32x4{0.f, 0.f, 0.f, 0.f};
    const int key0 = lm, key1 = 16 + lm;
#pragma unroll
    for (int ks = 0; ks < 8; ++ks) {
      f16x8 kf0 =
          *(const f16x8*)&kb[key0 * 256 + (((ks * 4 + g) ^ (key0 & 7)) * 8)];
      f16x8 kf1 =
          *(const f16x8*)&kb[key1 * 256 + (((ks * 4 + g) ^ (key1 & 7)) * 8)];
      s0 = MFMA16(qf[ks], kf0, s0);
      s1 = MFMA16(qf[ks], kf1, s1);
    }

    // ---- wave-local online softmax (DPP rowmax; l comes from ones-MFMA) ----
    f32x4 alpha;
    bool anyb = false;
#pragma unroll
    for (int r = 0; r < 4; ++r) {
      float mx = rowmax16(fmaxf(s0[r], s1[r]));
      float mnew = fmaxf(m_run[r], mx);
      alpha[r] = exp2f(m_run[r] - mnew);
      anyb |= (mnew > m_run[r]);
      m_run[r] = mnew;
      float p0 = exp2f(s0[r] - mnew);
      float p1 = exp2f(s1[r] - mnew);
      int row = wave * 16 + g * 4 + r;
      P_t[row * 72 + lm] = (_Float16)p0;
      P_t[row * 72 + 16 + lm] = (_Float16)p1;
    }
    if (lm == 0) *(f32x4*)&al_st[wave * 16 + g * 4] = alpha;
    unsigned long long bal = __ballot(anyb);
    if (lane == 0) bumped[wave] = (bal != 0ull) ? 1 : 0;
    __syncthreads();  // C: P_t/al_st/bumped visible; drains stage_k(it+1)

    // v prefetch for it+1: drained at next T with rescale+PV cover
    if (it < 63) {
      int mo = (it + 1) * 32;
#pragma unroll
      for (int ct = 0; ct < 4; ++ct)
        vfn[ct] = *(const f16x8*)(vbase[ct] + mo);
    }

    // ---- conditional O-rescale (per row-strip, scalar-branched) ----
#pragma unroll
    for (int nt = 0; nt < 8; ++nt) {
      if (__builtin_amdgcn_readfirstlane(bumped[nt])) {
        float a = al_st[nt * 16 + lm];
#pragma unroll
        for (int ct = 0; ct < 4; ++ct) {
          O[ct][nt][0] *= a; O[ct][nt][1] *= a;
          O[ct][nt][2] *= a; O[ct][nt][3] *= a;
        }
      }
    }
    if (__builtin_amdgcn_readfirstlane(bumped[wave])) {
      float a = al_st[wave * 16 + lm];
      Ol[0] *= a; Ol[1] *= a; Ol[2] *= a; Ol[3] *= a;
    }

    // ---- PV: O^T[c][n] += v[c][m] * P[n][m] ----
#pragma unroll
    for (int nt = 0; nt < 8; ++nt) {
      f16x8 pf = *(const f16x8*)&P_t[(nt * 16 + lm) * 72 + g * 8];
#pragma unroll
      for (int ct = 0; ct < 4; ++ct) O[ct][nt] = MFMA16(vf[ct], pf, O[ct][nt]);
    }
    {  // l for this wave's own 16 rows: D[m][n] = sum_k P[wave*16+n][k]
      f16x8 pfo = *(const f16x8*)&P_t[(wave * 16 + lm) * 72 + g * 8];
      Ol = MFMA16(ones, pfo, Ol);
    }
    if (it < 63) {
#pragma unroll
      for (int ct = 0; ct < 4; ++ct) vf[ct] = vfn[ct];
    }
  }

  // ---- epilogue: partial O + per-row m, l ----
  const size_t hb = (size_t)(b * 2 + h) * N_ + n0;
  if (lm == 0) {
#pragma unroll
    for (int r = 0; r < 4; ++r) mbuf[hb + wave * 16 + g * 4 + r] = m_run[r];
  }
  if (lane < 16) lbuf[hb + wave * 16 + lane] = Ol[0];

  if (h == 0) {
    float* ob = Op0 + (size_t)b * C_ * N_;
#pragma unroll
    for (int nt = 0; nt < 8; ++nt) {
      int n_g = n0 + nt * 16 + lm;
#pragma unroll
      for (int ct = 0; ct < 4; ++ct) {
        int cb = c0w + ct * 16 + g * 4;
#pragma unroll
        for (int r = 0; r < 4; ++r)
          ob[(size_t)(cb + r) * N_ + n_g] = O[ct][nt][r];
      }
    }
  } else {
    _Float16* ob = Op1 + (size_t)b * C_ * N_;
#pragma unroll
    for (int nt = 0; nt < 8; ++nt) {
      int n_g = n0 + nt * 16 + lm;
#pragma unroll
      for (int ct = 0; ct < 4; ++ct) {
        int cb = c0w + ct * 16 + g * 4;
#pragma unroll
        for (int r = 0; r < 4; ++r)
          ob[(size_t)(cb + r) * N_ + n_g] = (_Float16)O[ct][nt][r];
      }
    }
  }
}

// ---------------------------------------------------------------------------
// Kernel 4: combine the two K-halves + gamma scale + V residual.
// out = gamma * (a0*O0 + a1*O1) / (a0*l0 + a1*l1) + V
// ---------------------------------------------------------------------------
__global__ __launch_bounds__(256) void combine_kernel(
    float* __restrict__ out, const _Float16* __restrict__ Op1,
    const float* __restrict__ mbuf, const float* __restrict__ lbuf,
    const float* __restrict__ Vin, const float* __restrict__ gptr) {
  const int b = blockIdx.y;
  const int tid = threadIdx.x;
  const int n = blockIdx.x * 64 + (tid & 15) * 4;
  const int cg = tid >> 4;
  const float gamma = gptr[0];

  float s0[4], s1[4];
#pragma unroll
  for (int j = 0; j < 4; ++j) {
    float m0 = mbuf[(size_t)(b * 2 + 0) * N_ + n + j];
    float m1 = mbuf[(size_t)(b * 2 + 1) * N_ + n + j];
    float mx = fmaxf(m0, m1);
    float a0 = exp2f(m0 - mx), a1 = exp2f(m1 - mx);
    float l = a0 * lbuf[(size_t)(b * 2 + 0) * N_ + n + j] +
              a1 * lbuf[(size_t)(b * 2 + 1) * N_ + n + j];
    float inv = gamma / l;
    s0[j] = a0 * inv;
    s1[j] = a1 * inv;
  }

  const _Float16* O1b = Op1 + (size_t)b * C_ * N_;
  for (int c = cg * 32; c < cg * 32 + 32; ++c) {
    size_t idx = ((size_t)b * C_ + c) * N_ + n;
    f32x4 p0 = *(const f32x4*)(out + idx);
    f16x4 p1 = *(const f16x4*)(O1b + (size_t)c * N_ + n);
    f32x4 V = *(const f32x4*)(Vin + idx);
    f32x4 r;
#pragma unroll
    for (int j = 0; j < 4; ++j)
      r[j] = p0[j] * s0[j] + (float)p1[j] * s1[j] + V[j];
    *(f32x4*)(out + idx) = r;
  }
}

// ---------------------------------------------------------------------------
extern "C" void kernel_launch(void* const* d_in, const int* in_sizes, int n_in,
                              void* d_out, int out_size, void* d_ws, size_t ws_size,
                              hipStream_t stream) {
  const float* Q  = (const float*)d_in[0];
  const float* K  = (const float*)d_in[1];
  const float* V  = (const float*)d_in[2];
  const float* Wq = (const float*)d_in[3];
  const float* bq = (const float*)d_in[4];
  const float* Wk = (const float*)d_in[5];
  const float* bk = (const float*)d_in[6];
  const float* Wv = (const float*)d_in[7];
  const float* bv = (const float*)d_in[8];
  const float* gm = (const float*)d_in[9];
  float* out = (float*)d_out;

  // workspace carve (~42 MB)
  char* p = (char*)d_ws;
  _Float16* wq = (_Float16*)p; p += (size_t)CH_ * C_ * 2;
  _Float16* wk = (_Float16*)p; p += (size_t)CH_ * C_ * 2;
  _Float16* wv = (_Float16*)p; p += (size_t)C_ * C_ * 2;
  _Float16* qT = (_Float16*)p; p += (size_t)B_ * N_ * CH_ * 2;
  _Float16* kT = (_Float16*)p; p += (size_t)B_ * N_ * CH_ * 2;
  _Float16* vT = (_Float16*)p; p += (size_t)B_ * C_ * N_ * 2;
  _Float16* Op1 = (_Float16*)p; p += (size_t)B_ * C_ * N_ * 2;  // half-1 partial
  float* mbuf = (float*)p; p += (size_t)B_ * 2 * N_ * 4;
  float* lbuf = (float*)p; p += (size_t)B_ * 2 * N_ * 4;

  prep_w_kernel<<<(C_ * C_) / 256, 256, 0, stream>>>(Wq, Wk, Wv, wq, wk, wv);

  // fused q/k/v projections (y: 0=q, 1=k, 2,3=v halves)
  proj_kernel<<<dim3(N_ / 64, 4, B_), 512, 0, stream>>>(
      wq, wk, wv, Q, K, V, bq, bk, bv, qT, kT, vT);

  // split-K flash attention: half-0 partial -> d_out (fp32), half-1 -> Op1
  attn_kernel<<<256, 512, 0, stream>>>(qT, kT, vT, out, Op1, mbuf, lbuf);

  combine_kernel<<<dim3(N_ / 64, B_), 256, 0, stream>>>(out, Op1, mbuf, lbuf,
                                                        V, gm);
}